// Round 8
// baseline (229.521 us; speedup 1.0000x reference)
//
#include <hip/hip_runtime.h>

#define B_    64
#define S_    256
#define H_    768
#define A_    8
#define GNUM_ 8192
#define GSZ_  64
#define E_    256
#define TOPK_ 10
#define C_    (TOPK_*GSZ_)   // 640

typedef short  bf16x8 __attribute__((ext_vector_type(8)));
typedef float  f32x4  __attribute__((ext_vector_type(4)));

__device__ __forceinline__ ushort f2bf(float x) {
    union { float f; unsigned u; } c; c.f = x;
    unsigned r = c.u + 0x7fff + ((c.u >> 16) & 1);   // RNE
    return (ushort)(r >> 16);
}
__device__ __forceinline__ float bf2f(ushort h) {
    union { float f; unsigned u; } c; c.u = ((unsigned)h) << 16;
    return c.f;
}
__device__ __forceinline__ float asf(unsigned u) {
    union { unsigned u; float f; } c; c.u = u; return c.f;
}
__device__ __forceinline__ unsigned cvt_pk_bf16(float a, float b) {
    unsigned r;
    asm("v_cvt_pk_bf16_f32 %0, %1, %2" : "=v"(r) : "v"(a), "v"(b));
    return r;
}

// ---------------------------------------------------------------------------
// attn1: atten logits + bias.  Block (b, s-chunk of 64) -> attT[b][s][a].
// Also zeroes the gemm overflow-queue counter (block 0 only, every launch).
// ---------------------------------------------------------------------------
__global__ __launch_bounds__(256) void attn1_kernel(
    const float* __restrict__ x, const float* __restrict__ Watt,
    const float* __restrict__ batt, float* __restrict__ attT,
    unsigned* __restrict__ qcnt)
{
    const int b  = blockIdx.x;
    const int s0 = blockIdx.y * 64;
    const int t  = threadIdx.x;
    if (b == 0 && blockIdx.y == 0 && t == 0)
        __hip_atomic_store(qcnt, 0u, __ATOMIC_RELAXED, __HIP_MEMORY_SCOPE_AGENT);
    const int sl = t & 63;
    const int g  = __builtin_amdgcn_readfirstlane(t >> 6);
    __shared__ float Xt[64][65];
    __shared__ float Pp[8][64][5];

    const float* xb = x + ((size_t)b * S_ + s0) * H_;
    float acc[A_] = {};
    int pr[4], pc[4];
    float4 pref[4];
#pragma unroll
    for (int i = 0; i < 4; i++) {
        int fid = i * 256 + t;
        pr[i] = fid >> 4; pc[i] = (fid & 15) * 4;
    }
#pragma unroll
    for (int i = 0; i < 4; i++)
        pref[i] = *(const float4*)(xb + (size_t)pr[i] * H_ + pc[i]);
    for (int h0 = 0; h0 < H_; h0 += 64) {
        __syncthreads();
#pragma unroll
        for (int i = 0; i < 4; i++) {
            float4 v = pref[i];
            float* dst = &Xt[pr[i]][pc[i]];
            dst[0] = v.x; dst[1] = v.y; dst[2] = v.z; dst[3] = v.w;
        }
        __syncthreads();
        if (h0 + 64 < H_) {
#pragma unroll
            for (int i = 0; i < 4; i++)
                pref[i] = *(const float4*)(xb + (size_t)pr[i] * H_ + h0 + 64 + pc[i]);
        }
        const float* wp = Watt + h0 + g * 16;
#pragma unroll
        for (int h = 0; h < 16; h++) {
            float xv = Xt[sl][g * 16 + h];
#pragma unroll
            for (int a = 0; a < A_; a++) acc[a] += xv * wp[a * H_ + h];
        }
    }
#pragma unroll
    for (int a = 0; a < A_; a++) Pp[a][sl][g] = acc[a];
    __syncthreads();
#pragma unroll
    for (int i = 0; i < 2; i++) {
        int idx = i * 256 + t;
        int a = idx >> 6, s2 = idx & 63;
        float v = Pp[a][s2][0] + Pp[a][s2][1] + Pp[a][s2][2] + Pp[a][s2][3] + batt[a];
        attT[(size_t)b * (S_*A_) + (size_t)(s0 + s2) * A_ + a] = v;
    }
}

// ---------------------------------------------------------------------------
// attn2s: inline softmax + weighted sum + bf16 hi/lo split.
// Block (b, h-tile of 256); 16-strip software-pipelined x loads.
// ---------------------------------------------------------------------------
__global__ __launch_bounds__(256) void attn2s_kernel(
    const float* __restrict__ x, const float* __restrict__ attT,
    ushort* __restrict__ Ah, ushort* __restrict__ Al)
{
    const int b = blockIdx.x, h0 = blockIdx.y * 256, t = threadIdx.x;
    __shared__ float La[S_ * A_];          // [s][a]
    __shared__ float Wm[A_][260];          // [a][s]

#pragma unroll
    for (int i = 0; i < 2; i++) {
        int fid = i * 256 + t;
        *(float4*)&La[fid * 4] =
            *(const float4*)(attT + (size_t)b * (S_*A_) + (size_t)fid * 4);
    }
    __syncthreads();
    {
        const int a = t >> 5, l = t & 31;
        float mx = -1e30f;
#pragma unroll
        for (int k = 0; k < 8; k++) mx = fmaxf(mx, La[(l + 32*k) * A_ + a]);
#pragma unroll
        for (int off = 16; off >= 1; off >>= 1) mx = fmaxf(mx, __shfl_xor(mx, off));
        float ev[8]; float sm = 0.f;
#pragma unroll
        for (int k = 0; k < 8; k++) { ev[k] = expf(La[(l + 32*k) * A_ + a] - mx); sm += ev[k]; }
#pragma unroll
        for (int off = 16; off >= 1; off >>= 1) sm += __shfl_xor(sm, off);
        float inv = 1.f / sm;
#pragma unroll
        for (int k = 0; k < 8; k++) Wm[a][l + 32*k] = ev[k] * inv;
    }
    __syncthreads();

    const float* xb = x + (size_t)b * S_ * H_ + h0 + t;
    float o[A_] = {};
    float xb0[16], xb1[16];
#define LOADSTRIP(buf, ks) { _Pragma("unroll") \
    for (int i = 0; i < 16; i++) buf[i] = xb[(size_t)((ks)*16 + i) * H_]; }
#define COMPSTRIP(buf, ks) { _Pragma("unroll") \
    for (int sg = 0; sg < 4; sg++) { _Pragma("unroll") \
        for (int a = 0; a < A_; a++) { \
            float4 w2 = *(const float4*)&Wm[a][(ks)*16 + sg*4]; \
            o[a] += w2.x*buf[sg*4+0] + w2.y*buf[sg*4+1] \
                  + w2.z*buf[sg*4+2] + w2.w*buf[sg*4+3]; } } }
    LOADSTRIP(xb0, 0)
#pragma unroll
    for (int kp = 0; kp < 8; kp++) {
        LOADSTRIP(xb1, 2*kp + 1)
        COMPSTRIP(xb0, 2*kp)
        if (kp < 7) LOADSTRIP(xb0, 2*kp + 2)
        COMPSTRIP(xb1, 2*kp + 1)
    }
#undef LOADSTRIP
#undef COMPSTRIP
#pragma unroll
    for (int a = 0; a < A_; a++) {
        float v = o[a];
        ushort hi = f2bf(v);
        ushort lo = f2bf(v - bf2f(hi));
        size_t off = (size_t)(b * 8 + a) * H_ + h0 + t;
        Ah[off] = hi; Al[off] = lo;
    }
}

// ---------------------------------------------------------------------------
// gemm: A(512x768) x B^T(8448x768), bf16x3 MFMA, B split hi/lo in-register.
// Grid = 256 blocks: 256 static clf tiles (XCD swizzle) + 8 enc tiles via
// atomic overflow queue.  clf epilogue: head-max -> c_out AND per-row top-10
// of sigmoid -> t10v/t10i.  enc epilogue: embw.
// ---------------------------------------------------------------------------
__global__ __launch_bounds__(256, 1) void gemm_mfma_kernel(
    const ushort* __restrict__ Ah, const ushort* __restrict__ Al,
    const float* __restrict__ Wclf, const float* __restrict__ Wenc,
    const float* __restrict__ bclf, const float* __restrict__ benc,
    float* __restrict__ c_out, float* __restrict__ emb,
    float* __restrict__ t10v, int* __restrict__ t10i,
    unsigned* __restrict__ qcnt)
{
    __shared__ __align__(16) ushort lds[2][4][128 * 32];   // 64 KB
    __shared__ unsigned jtile;
    const int t = threadIdx.x;
    const int w = t >> 6, l = t & 63;
    const int mq = (w & 1) * 64, nq = (w >> 1) * 64;
    const int srow = t >> 2, skc = t & 3;
    const int wr_idx = ((srow * 32 + skc * 8) ^ ((srow & 7) << 3));
    const int kc = l >> 4, lr = l & 15;

    // static tile from XCD swizzle
    int p = (blockIdx.x & 7) + 8 * ((blockIdx.x >> 3) >> 2);   // 0..63
    int m = (blockIdx.x >> 3) & 3;

    for (int iter = 0; ; iter++) {
        if (iter > 0) {                     // pop enc tile from queue
            __syncthreads();
            if (t == 0) jtile = atomicAdd(qcnt, 1u);
            __syncthreads();
            unsigned j = jtile;
            if (j >= 8u) break;
            p = 64 + (int)(j >> 2);         // 64..65
            m = (int)(j & 3);
        }
        const int n0 = p * 128, m0 = m * 128;
        const ushort* baseAh = Ah + (size_t)m0 * H_;
        const ushort* baseAl = Al + (size_t)m0 * H_;
        const float*  baseB  = (n0 < GNUM_) ? (Wclf + (size_t)n0 * H_)
                                            : (Wenc + (size_t)(n0 - GNUM_) * H_);
        uint4  stA[2][2];
        float4 stB[2][2];
        auto loadk = [&](int k0) {
            size_t oA = (size_t)srow * H_ + k0 + skc * 8;
            stA[0][0] = *(const uint4*)(baseAh + oA);
            stA[0][1] = *(const uint4*)(baseAh + oA + (size_t)64 * H_);
            stA[1][0] = *(const uint4*)(baseAl + oA);
            stA[1][1] = *(const uint4*)(baseAl + oA + (size_t)64 * H_);
            const float* bp0 = baseB + (size_t)srow * H_ + k0 + skc * 8;
            const float* bp1 = bp0 + (size_t)64 * H_;
            stB[0][0] = *(const float4*)(bp0);
            stB[0][1] = *(const float4*)(bp0 + 4);
            stB[1][0] = *(const float4*)(bp1);
            stB[1][1] = *(const float4*)(bp1 + 4);
        };

        f32x4 acc[4][4] = {};
        loadk(0);

        for (int kt = 0; kt < H_ / 32; ++kt) {
            ushort* bufp = &lds[kt & 1][0][0];
            if (iter > 0 && kt == 0) __syncthreads();   // guard LDS reuse
#pragma unroll
            for (int xx = 0; xx < 2; xx++) {
                *(uint4*)(bufp + xx * 4096 + wr_idx)        = stA[xx][0];
                *(uint4*)(bufp + xx * 4096 + 2048 + wr_idx) = stA[xx][1];
            }
#pragma unroll
            for (int rp = 0; rp < 2; rp++) {
                float fv[8] = { stB[rp][0].x, stB[rp][0].y, stB[rp][0].z, stB[rp][0].w,
                                stB[rp][1].x, stB[rp][1].y, stB[rp][1].z, stB[rp][1].w };
                uint4 hi, lo;
                unsigned* hip = (unsigned*)&hi;
                unsigned* lop = (unsigned*)&lo;
#pragma unroll
                for (int j2 = 0; j2 < 4; j2++) {
                    unsigned pk = cvt_pk_bf16(fv[2*j2], fv[2*j2+1]);
                    hip[j2] = pk;
                    float r0 = fv[2*j2]   - asf(pk << 16);
                    float r1 = fv[2*j2+1] - asf(pk & 0xffff0000u);
                    lop[j2] = cvt_pk_bf16(r0, r1);
                }
                *(uint4*)(bufp + 2 * 4096 + rp * 2048 + wr_idx) = hi;
                *(uint4*)(bufp + 3 * 4096 + rp * 2048 + wr_idx) = lo;
            }
            __syncthreads();
            if (kt + 1 < H_ / 32) loadk((kt + 1) * 32);

            bf16x8 fah[4], fal[4], fbh[4], fbl[4];
#pragma unroll
            for (int mt = 0; mt < 4; mt++) {
                int r = mq + mt * 16 + lr;
                int idx = ((r * 32 + kc * 8) ^ ((r & 7) << 3));
                fah[mt] = *(const bf16x8*)(bufp + idx);
                fal[mt] = *(const bf16x8*)(bufp + 4096 + idx);
            }
#pragma unroll
            for (int nt = 0; nt < 4; nt++) {
                int r = nq + nt * 16 + lr;
                int idx = ((r * 32 + kc * 8) ^ ((r & 7) << 3));
                fbh[nt] = *(const bf16x8*)(bufp + 2 * 4096 + idx);
                fbl[nt] = *(const bf16x8*)(bufp + 3 * 4096 + idx);
            }
#pragma unroll
            for (int mt = 0; mt < 4; mt++)
#pragma unroll
                for (int nt = 0; nt < 4; nt++) {
                    acc[mt][nt] = __builtin_amdgcn_mfma_f32_16x16x32_bf16(fah[mt], fbh[nt], acc[mt][nt], 0, 0, 0);
                    acc[mt][nt] = __builtin_amdgcn_mfma_f32_16x16x32_bf16(fal[mt], fbh[nt], acc[mt][nt], 0, 0, 0);
                    acc[mt][nt] = __builtin_amdgcn_mfma_f32_16x16x32_bf16(fah[mt], fbl[nt], acc[mt][nt], 0, 0, 0);
                }
        }

        const int q = l >> 4;
        if (n0 < GNUM_) {
            float* Pm = (float*)&lds[0][0][0];        // [16][128] f32 overlay
#pragma unroll
            for (int mt = 0; mt < 4; mt++)
#pragma unroll
                for (int nt = 0; nt < 4; nt++) {
                    f32x4 a = acc[mt][nt];
                    float v = fmaxf(fmaxf(a[0], a[1]), fmaxf(a[2], a[3]));
                    v = fmaxf(v, __shfl_xor(v, 16));
                    if ((q & 1) == 0) {
                        int r16 = (mq >> 3) + 2 * mt + (q >> 1);
                        int col = nq + nt * 16 + lr;
                        int n   = n0 + col;
                        float logit = v + bclf[n];
                        c_out[(size_t)((m0 >> 3) + r16) * GNUM_ + n] = logit;
                        Pm[r16 * 128 + col] = 1.f / (1.f + expf(-logit));
                    }
                }
            __syncthreads();
            // per-row top-10 of probs (tie: lower index).  Wave w: rows w*4..+3
#pragma unroll
            for (int rr = 0; rr < 4; rr++) {
                int r = w * 4 + rr;
                float p0 = Pm[r * 128 + l];
                float p1 = Pm[r * 128 + 64 + l];
                int bg = (m0 >> 3) + r;
                size_t tb = ((size_t)bg * 64 + p) * TOPK_;
                for (int k = 0; k < TOPK_; k++) {
                    float bv; int bi;
                    if (p0 >= p1) { bv = p0; bi = l; } else { bv = p1; bi = 64 + l; }
#pragma unroll
                    for (int off = 32; off >= 1; off >>= 1) {
                        float ov = __shfl_xor(bv, off); int oi = __shfl_xor(bi, off);
                        if (ov > bv || (ov == bv && oi < bi)) { bv = ov; bi = oi; }
                    }
                    if (l == 0) { t10v[tb + k] = bv; t10i[tb + k] = n0 + bi; }
                    if (bi < 64) { if (l == bi) p0 = -1.f; }
                    else         { if (l == bi - 64) p1 = -1.f; }
                }
            }
        } else {
#pragma unroll
            for (int mt = 0; mt < 4; mt++)
#pragma unroll
                for (int nt = 0; nt < 4; nt++) {
                    int n = n0 - GNUM_ + nq + nt * 16 + lr;
                    float bn = benc[n];
#pragma unroll
                    for (int r2 = 0; r2 < 4; r2++) {
                        int mg = m0 + mq + mt * 16 + q * 4 + r2;
                        emb[(size_t)mg * E_ + n] = acc[mt][nt][r2] + bn;
                    }
                }
        }
    }
}

// ---------------------------------------------------------------------------
// scoretop: block (b, quarter).  Merge 64 panels x top-10 -> exact global
// top-10 (same tie-break), emit cand_f/gcs slice, score 160 candidates.
// ---------------------------------------------------------------------------
__global__ __launch_bounds__(256) void scoretop_kernel(
    const float* __restrict__ t10v, const int* __restrict__ t10i,
    const float* __restrict__ embw, const float* __restrict__ et,
    const int* __restrict__ gy,
    float* __restrict__ l_out, float* __restrict__ cand_f,
    float* __restrict__ gcs)
{
    const int b = blockIdx.x >> 2, q4 = blockIdx.x & 3, t = threadIdx.x;
    __shared__ float el[A_ * E_];          // 8 KB
    __shared__ float tvs[640];
    __shared__ int   tis[640];
    __shared__ float bvv[4]; __shared__ int bii[4];
    __shared__ float topv[TOPK_]; __shared__ int topi[TOPK_];

#pragma unroll
    for (int i = 0; i < 2; i++) {
        int fid = i * 256 + t;
        *(float4*)&el[fid * 4] = *(const float4*)(embw + (size_t)b * (A_*E_) + fid * 4);
    }
    for (int j = t; j < 640; j += 256) {
        tvs[j] = t10v[(size_t)b * 640 + j];
        tis[j] = t10i[(size_t)b * 640 + j];
    }
    __syncthreads();

    // per-thread top-10 over its <=3 entries (ascending global idx in-thread)
    float lv[TOPK_]; int li[TOPK_];
#pragma unroll
    for (int k = 0; k < TOPK_; k++) { lv[k] = -1.f; li[k] = 0x7fffffff; }
    for (int j = t; j < 640; j += 256) {
        float pv = tvs[j]; int gi = tis[j];
        if (pv > lv[TOPK_ - 1]) {
            float cv = pv; int ci = gi;
#pragma unroll
            for (int k = 0; k < TOPK_; k++) {
                bool sw = (cv > lv[k]);
                float tv = sw ? lv[k] : cv; int ti = sw ? li[k] : ci;
                lv[k] = sw ? cv : lv[k];    li[k] = sw ? ci : li[k];
                cv = tv; ci = ti;
            }
        }
    }
    const int lane = t & 63, wv = t >> 6;
    for (int rnd = 0; rnd < TOPK_; rnd++) {
        float bv = lv[0]; int bi = li[0];
#pragma unroll
        for (int off = 32; off >= 1; off >>= 1) {
            float ov = __shfl_xor(bv, off); int oi = __shfl_xor(bi, off);
            if (ov > bv || (ov == bv && oi < bi)) { bv = ov; bi = oi; }
        }
        if (lane == 0) { bvv[wv] = bv; bii[wv] = bi; }
        __syncthreads();
        float gbv = bvv[0]; int gbi = bii[0];
#pragma unroll
        for (int w2 = 1; w2 < 4; w2++) {
            float ov = bvv[w2]; int oi = bii[w2];
            if (ov > gbv || (ov == gbv && oi < gbi)) { gbv = ov; gbi = oi; }
        }
        if (t == 0) { topv[rnd] = gbv; topi[rnd] = gbi; }
        if (li[0] == gbi) {
#pragma unroll
            for (int k = 0; k < TOPK_ - 1; k++) { lv[k] = lv[k + 1]; li[k] = li[k + 1]; }
            lv[TOPK_ - 1] = -1.f; li[TOPK_ - 1] = 0x7fffffff;
        }
        __syncthreads();
    }

    const int cbase = q4 * 160;
    if (t < 160) {
        int c = cbase + t;
        int k = c >> 6, slot = c & 63;
        int lbl = gy[topi[k] * GSZ_ + slot];
        cand_f[(size_t)b * C_ + c] = (float)lbl;
        gcs[(size_t)b * C_ + c] = topv[k];
    }

    // score this quarter's 160 candidates
    const int qq = lane >> 4, sub = lane & 15;
    int c = cbase + wv * 4 + qq;
    int lbl0 = gy[topi[c >> 6] * GSZ_ + (c & 63)];
    const float* er = et + (size_t)lbl0 * E_ + sub * 4;
    float4 v0 = *(const float4*)(er);
    float4 v1 = *(const float4*)(er + 64);
    float4 v2 = *(const float4*)(er + 128);
    float4 v3 = *(const float4*)(er + 192);
    for (int pass = 0; pass < 10; pass++) {
        float4 p0, p1, p2, p3;
        if (pass + 1 < 10) {
            int cn = cbase + (pass + 1) * 16 + wv * 4 + qq;
            int lbln = gy[topi[cn >> 6] * GSZ_ + (cn & 63)];
            const float* ern = et + (size_t)lbln * E_ + sub * 4;
            p0 = *(const float4*)(ern);
            p1 = *(const float4*)(ern + 64);
            p2 = *(const float4*)(ern + 128);
            p3 = *(const float4*)(ern + 192);
        }
        float best = -1e30f;
#pragma unroll
        for (int a = 0; a < A_; a++) {
            const float* ep = el + a * E_ + sub * 4;
            float4 w0 = *(const float4*)(ep);
            float4 w1 = *(const float4*)(ep + 64);
            float4 w2 = *(const float4*)(ep + 128);
            float4 w3 = *(const float4*)(ep + 192);
            float pp = v0.x*w0.x + v0.y*w0.y + v0.z*w0.z + v0.w*w0.w
                     + v1.x*w1.x + v1.y*w1.y + v1.z*w1.z + v1.w*w1.w
                     + v2.x*w2.x + v2.y*w2.y + v2.z*w2.z + v2.w*w2.w
                     + v3.x*w3.x + v3.y*w3.y + v3.z*w3.z + v3.w*w3.w;
#pragma unroll
            for (int off = 8; off >= 1; off >>= 1) pp += __shfl_xor(pp, off);
            best = fmaxf(best, pp);
        }
        if (sub == 0) l_out[(size_t)b * C_ + cbase + pass * 16 + wv * 4 + qq] = best;
        v0 = p0; v1 = p1; v2 = p2; v3 = p3;
    }
}

// ---------------------------------------------------------------------------
extern "C" void kernel_launch(void* const* d_in, const int* in_sizes, int n_in,
                              void* d_out, int out_size, void* d_ws, size_t ws_size,
                              hipStream_t stream)
{
    (void)in_sizes; (void)n_in; (void)out_size; (void)ws_size;
    const float* x    = (const float*)d_in[0];
    const float* Watt = (const float*)d_in[1];
    const float* batt = (const float*)d_in[2];
    const float* Wclf = (const float*)d_in[3];
    const float* bclf = (const float*)d_in[4];
    const float* Wenc = (const float*)d_in[5];
    const float* benc = (const float*)d_in[6];
    const float* et   = (const float*)d_in[7];
    const int*   gy   = (const int*)d_in[8];

    float* out    = (float*)d_out;
    float* c_out  = out;                        // [64][8192]
    float* l_out  = out + (size_t)B_ * GNUM_;   // [64][640]
    float* cand_f = l_out + (size_t)B_ * C_;    // [64][640]
    float* gcs    = cand_f + (size_t)B_ * C_;   // [64][640]

    char* ws = (char*)d_ws;
    float*    attT = (float*)   (ws);                 // 512 KB
    float*    embw = (float*)   (ws + 524288);        // 512 KB
    ushort*   Ahw  = (ushort*)  (ws + 1048576);       // 768 KB
    ushort*   Alw  = (ushort*)  (ws + 1835008);       // 768 KB
    float*    t10v = (float*)   (ws + 2621440);       // 160 KB
    int*      t10i = (int*)     (ws + 2785280);       // 160 KB
    unsigned* qcnt = (unsigned*)(ws + 2949120);       // 4 B

    attn1_kernel<<<dim3(B_, 4), 256, 0, stream>>>(x, Watt, batt, attT, qcnt);
    attn2s_kernel<<<dim3(B_, 3), 256, 0, stream>>>(x, attT, Ahw, Alw);
    gemm_mfma_kernel<<<256, 256, 0, stream>>>(Ahw, Alw, Wclf, Wenc, bclf, benc,
                                              c_out, embw, t10v, t10i, qcnt);
    scoretop_kernel<<<256, 256, 0, stream>>>(t10v, t10i, embw, et, gy,
                                             l_out, cand_f, gcs);
}

// Round 9
// 141.034 us; speedup vs baseline: 1.6274x; 1.6274x over previous
//
#include <hip/hip_runtime.h>

#define B_    64
#define S_    256
#define H_    768
#define A_    8
#define GNUM_ 8192
#define GSZ_  64
#define E_    256
#define TOPK_ 10
#define C_    (TOPK_*GSZ_)   // 640
#define BROWS (GNUM_ + E_)   // 8448

typedef short  bf16x8 __attribute__((ext_vector_type(8)));
typedef float  f32x4  __attribute__((ext_vector_type(4)));

__device__ __forceinline__ ushort f2bf(float x) {
    union { float f; unsigned u; } c; c.f = x;
    unsigned r = c.u + 0x7fff + ((c.u >> 16) & 1);   // RNE
    return (ushort)(r >> 16);
}
__device__ __forceinline__ float bf2f(ushort h) {
    union { float f; unsigned u; } c; c.u = ((unsigned)h) << 16;
    return c.f;
}
__device__ __forceinline__ float asf(unsigned u) {
    union { unsigned u; float f; } c; c.u = u; return c.f;
}
__device__ __forceinline__ unsigned cvt_pk_bf16(float a, float b) {
    unsigned r;
    asm("v_cvt_pk_bf16_f32 %0, %1, %2" : "=v"(r) : "v"(a), "v"(b));
    return r;
}

// ---------------------------------------------------------------------------
// attn1: atten logits + bias.  Block (b, s-chunk of 64) -> attT[b][s][a].
// Register-prefetched staging (R5-form).
// ---------------------------------------------------------------------------
__global__ __launch_bounds__(256) void attn1_kernel(
    const float* __restrict__ x, const float* __restrict__ Watt,
    const float* __restrict__ batt, float* __restrict__ attT)
{
    const int b  = blockIdx.x;
    const int s0 = blockIdx.y * 64;
    const int t  = threadIdx.x;
    const int sl = t & 63;
    const int g  = __builtin_amdgcn_readfirstlane(t >> 6);
    __shared__ float Xt[64][65];
    __shared__ float Pp[8][64][5];

    const float* xb = x + ((size_t)b * S_ + s0) * H_;
    float acc[A_] = {};
    int pr[4], pc[4];
    float4 pref[4];
#pragma unroll
    for (int i = 0; i < 4; i++) {
        int fid = i * 256 + t;
        pr[i] = fid >> 4; pc[i] = (fid & 15) * 4;
    }
#pragma unroll
    for (int i = 0; i < 4; i++)
        pref[i] = *(const float4*)(xb + (size_t)pr[i] * H_ + pc[i]);
    for (int h0 = 0; h0 < H_; h0 += 64) {
        __syncthreads();
#pragma unroll
        for (int i = 0; i < 4; i++) {
            float4 v = pref[i];
            float* dst = &Xt[pr[i]][pc[i]];
            dst[0] = v.x; dst[1] = v.y; dst[2] = v.z; dst[3] = v.w;
        }
        __syncthreads();
        if (h0 + 64 < H_) {
#pragma unroll
            for (int i = 0; i < 4; i++)
                pref[i] = *(const float4*)(xb + (size_t)pr[i] * H_ + h0 + 64 + pc[i]);
        }
        const float* wp = Watt + h0 + g * 16;
#pragma unroll
        for (int h = 0; h < 16; h++) {
            float xv = Xt[sl][g * 16 + h];
#pragma unroll
            for (int a = 0; a < A_; a++) acc[a] += xv * wp[a * H_ + h];
        }
    }
#pragma unroll
    for (int a = 0; a < A_; a++) Pp[a][sl][g] = acc[a];
    __syncthreads();
#pragma unroll
    for (int i = 0; i < 2; i++) {
        int idx = i * 256 + t;
        int a = idx >> 6, s2 = idx & 63;
        float v = Pp[a][s2][0] + Pp[a][s2][1] + Pp[a][s2][2] + Pp[a][s2][3] + batt[a];
        attT[(size_t)b * (S_*A_) + (size_t)(s0 + s2) * A_ + a] = v;
    }
}

// ---------------------------------------------------------------------------
// attn2s: inline softmax + weighted sum + bf16 hi/lo split.
// Block (b, h-tile of 256); 16-strip software-pipelined x loads.
// ---------------------------------------------------------------------------
__global__ __launch_bounds__(256) void attn2s_kernel(
    const float* __restrict__ x, const float* __restrict__ attT,
    ushort* __restrict__ Ah, ushort* __restrict__ Al)
{
    const int b = blockIdx.x, h0 = blockIdx.y * 256, t = threadIdx.x;
    __shared__ float La[S_ * A_];          // [s][a]
    __shared__ float Wm[A_][260];          // [a][s]

#pragma unroll
    for (int i = 0; i < 2; i++) {
        int fid = i * 256 + t;
        *(float4*)&La[fid * 4] =
            *(const float4*)(attT + (size_t)b * (S_*A_) + (size_t)fid * 4);
    }
    __syncthreads();
    {
        const int a = t >> 5, l = t & 31;
        float mx = -1e30f;
#pragma unroll
        for (int k = 0; k < 8; k++) mx = fmaxf(mx, La[(l + 32*k) * A_ + a]);
#pragma unroll
        for (int off = 16; off >= 1; off >>= 1) mx = fmaxf(mx, __shfl_xor(mx, off));
        float ev[8]; float sm = 0.f;
#pragma unroll
        for (int k = 0; k < 8; k++) { ev[k] = expf(La[(l + 32*k) * A_ + a] - mx); sm += ev[k]; }
#pragma unroll
        for (int off = 16; off >= 1; off >>= 1) sm += __shfl_xor(sm, off);
        float inv = 1.f / sm;
#pragma unroll
        for (int k = 0; k < 8; k++) Wm[a][l + 32*k] = ev[k] * inv;
    }
    __syncthreads();

    const float* xb = x + (size_t)b * S_ * H_ + h0 + t;
    float o[A_] = {};
    float xb0[16], xb1[16];
#define LOADSTRIP(buf, ks) { _Pragma("unroll") \
    for (int i = 0; i < 16; i++) buf[i] = xb[(size_t)((ks)*16 + i) * H_]; }
#define COMPSTRIP(buf, ks) { _Pragma("unroll") \
    for (int sg = 0; sg < 4; sg++) { _Pragma("unroll") \
        for (int a = 0; a < A_; a++) { \
            float4 w2 = *(const float4*)&Wm[a][(ks)*16 + sg*4]; \
            o[a] += w2.x*buf[sg*4+0] + w2.y*buf[sg*4+1] \
                  + w2.z*buf[sg*4+2] + w2.w*buf[sg*4+3]; } } }
    LOADSTRIP(xb0, 0)
#pragma unroll
    for (int kp = 0; kp < 8; kp++) {
        LOADSTRIP(xb1, 2*kp + 1)
        COMPSTRIP(xb0, 2*kp)
        if (kp < 7) LOADSTRIP(xb0, 2*kp + 2)
        COMPSTRIP(xb1, 2*kp + 1)
    }
#undef LOADSTRIP
#undef COMPSTRIP
#pragma unroll
    for (int a = 0; a < A_; a++) {
        float v = o[a];
        ushort hi = f2bf(v);
        ushort lo = f2bf(v - bf2f(hi));
        size_t off = (size_t)(b * 8 + a) * H_ + h0 + t;
        Ah[off] = hi; Al[off] = lo;
    }
}

// ---------------------------------------------------------------------------
// gemm: C = A(512x768) x B^T(8448x768), bf16x3 MFMA (AhBh + AlBh + AhBl).
// B staged from f32 and split hi/lo in-register.  128x128 tile, BK=32,
// XOR-swizzled LDS, XCD swizzle.  Grid 288 (R4-identical, tail returns).
// ---------------------------------------------------------------------------
__global__ __launch_bounds__(256, 1) void gemm_mfma_kernel(
    const ushort* __restrict__ Ah, const ushort* __restrict__ Al,
    const float* __restrict__ Wclf, const float* __restrict__ Wenc,
    const float* __restrict__ bclf, const float* __restrict__ benc,
    float* __restrict__ c_out, float* __restrict__ emb)
{
    const int f = blockIdx.x;
    const int xcd = f & 7, s = f >> 3;
    const int p = xcd + 8 * (s >> 2);          // B panel 0..65 (+invalid tail)
    const int m = s & 3;
    if (p >= BROWS / 128) return;
    const int n0 = p * 128, m0 = m * 128;

    __shared__ __align__(16) ushort lds[2][4][128 * 32];   // 64 KB
    const int t = threadIdx.x;
    const int w = t >> 6, l = t & 63;
    const int mq = (w & 1) * 64, nq = (w >> 1) * 64;

    const int srow = t >> 2, skc = t & 3;
    const int wr_idx = ((srow * 32 + skc * 8) ^ ((srow & 7) << 3));
    const ushort* baseAh = Ah + (size_t)m0 * H_;
    const ushort* baseAl = Al + (size_t)m0 * H_;
    const float*  baseB  = (n0 < GNUM_) ? (Wclf + (size_t)n0 * H_)
                                        : (Wenc + (size_t)(n0 - GNUM_) * H_);

    uint4  stA[2][2];
    float4 stB[2][2];
    auto loadk = [&](int k0) {
        size_t oA = (size_t)srow * H_ + k0 + skc * 8;
        stA[0][0] = *(const uint4*)(baseAh + oA);
        stA[0][1] = *(const uint4*)(baseAh + oA + (size_t)64 * H_);
        stA[1][0] = *(const uint4*)(baseAl + oA);
        stA[1][1] = *(const uint4*)(baseAl + oA + (size_t)64 * H_);
        const float* bp0 = baseB + (size_t)srow * H_ + k0 + skc * 8;
        const float* bp1 = bp0 + (size_t)64 * H_;
        stB[0][0] = *(const float4*)(bp0);
        stB[0][1] = *(const float4*)(bp0 + 4);
        stB[1][0] = *(const float4*)(bp1);
        stB[1][1] = *(const float4*)(bp1 + 4);
    };

    f32x4 acc[4][4] = {};
    loadk(0);
    const int kc = l >> 4, lr = l & 15;

    for (int kt = 0; kt < H_ / 32; ++kt) {
        ushort* bufp = &lds[kt & 1][0][0];
#pragma unroll
        for (int xx = 0; xx < 2; xx++) {
            *(uint4*)(bufp + xx * 4096 + wr_idx)        = stA[xx][0];
            *(uint4*)(bufp + xx * 4096 + 2048 + wr_idx) = stA[xx][1];
        }
#pragma unroll
        for (int rp = 0; rp < 2; rp++) {
            float fv[8] = { stB[rp][0].x, stB[rp][0].y, stB[rp][0].z, stB[rp][0].w,
                            stB[rp][1].x, stB[rp][1].y, stB[rp][1].z, stB[rp][1].w };
            uint4 hi, lo;
            unsigned* hip = (unsigned*)&hi;
            unsigned* lop = (unsigned*)&lo;
#pragma unroll
            for (int j = 0; j < 4; j++) {
                unsigned pk = cvt_pk_bf16(fv[2*j], fv[2*j+1]);
                hip[j] = pk;
                float r0 = fv[2*j]   - asf(pk << 16);
                float r1 = fv[2*j+1] - asf(pk & 0xffff0000u);
                lop[j] = cvt_pk_bf16(r0, r1);
            }
            *(uint4*)(bufp + 2 * 4096 + rp * 2048 + wr_idx) = hi;
            *(uint4*)(bufp + 3 * 4096 + rp * 2048 + wr_idx) = lo;
        }
        __syncthreads();
        if (kt + 1 < H_ / 32) loadk((kt + 1) * 32);

        bf16x8 fah[4], fal[4], fbh[4], fbl[4];
#pragma unroll
        for (int mt = 0; mt < 4; mt++) {
            int r = mq + mt * 16 + lr;
            int idx = ((r * 32 + kc * 8) ^ ((r & 7) << 3));
            fah[mt] = *(const bf16x8*)(bufp + idx);
            fal[mt] = *(const bf16x8*)(bufp + 4096 + idx);
        }
#pragma unroll
        for (int nt = 0; nt < 4; nt++) {
            int r = nq + nt * 16 + lr;
            int idx = ((r * 32 + kc * 8) ^ ((r & 7) << 3));
            fbh[nt] = *(const bf16x8*)(bufp + 2 * 4096 + idx);
            fbl[nt] = *(const bf16x8*)(bufp + 3 * 4096 + idx);
        }
#pragma unroll
        for (int mt = 0; mt < 4; mt++)
#pragma unroll
            for (int nt = 0; nt < 4; nt++) {
                acc[mt][nt] = __builtin_amdgcn_mfma_f32_16x16x32_bf16(fah[mt], fbh[nt], acc[mt][nt], 0, 0, 0);
                acc[mt][nt] = __builtin_amdgcn_mfma_f32_16x16x32_bf16(fal[mt], fbh[nt], acc[mt][nt], 0, 0, 0);
                acc[mt][nt] = __builtin_amdgcn_mfma_f32_16x16x32_bf16(fah[mt], fbl[nt], acc[mt][nt], 0, 0, 0);
            }
    }

    const int q = l >> 4;
    if (n0 < GNUM_) {
#pragma unroll
        for (int mt = 0; mt < 4; mt++)
#pragma unroll
            for (int nt = 0; nt < 4; nt++) {
                f32x4 a = acc[mt][nt];
                float v = fmaxf(fmaxf(a[0], a[1]), fmaxf(a[2], a[3]));
                v = fmaxf(v, __shfl_xor(v, 16));
                if ((q & 1) == 0) {
                    int mg = m0 + mq + mt * 16 + (q >> 1) * 8;
                    int n  = n0 + nq + nt * 16 + lr;
                    c_out[(size_t)(mg >> 3) * GNUM_ + n] = v + bclf[n];
                }
            }
    } else {
#pragma unroll
        for (int mt = 0; mt < 4; mt++)
#pragma unroll
            for (int nt = 0; nt < 4; nt++) {
                int n = n0 - GNUM_ + nq + nt * 16 + lr;
                float bn = benc[n];
#pragma unroll
                for (int r2 = 0; r2 < 4; r2++) {
                    int mg = m0 + mq + mt * 16 + q * 4 + r2;
                    emb[(size_t)mg * E_ + n] = acc[mt][nt][r2] + bn;
                }
            }
    }
}

// ---------------------------------------------------------------------------
// scoretop: block (b, quarter).  Each block recomputes row-b top-10 from
// c_out (identical scan/tie-break as R4 topk), block q4==0 writes cand_f/gcs,
// all blocks score their 160-candidate quarter.
// ---------------------------------------------------------------------------
__global__ __launch_bounds__(256) void scoretop_kernel(
    const float* __restrict__ c_out, const int* __restrict__ gy,
    const float* __restrict__ embw, const float* __restrict__ et,
    float* __restrict__ l_out, float* __restrict__ cand_f,
    float* __restrict__ gcs)
{
    const int b = blockIdx.x >> 2, q4 = blockIdx.x & 3, t = threadIdx.x;
    __shared__ float el[A_ * E_];          // 8 KB
    __shared__ float bvv[4]; __shared__ int bii[4];
    __shared__ float topv[TOPK_]; __shared__ int topi[TOPK_];

#pragma unroll
    for (int i = 0; i < 2; i++) {
        int fid = i * 256 + t;
        *(float4*)&el[fid * 4] = *(const float4*)(embw + (size_t)b * (A_*E_) + fid * 4);
    }

    // ---- top-10 of sigmoid(c_out[b]) — verbatim R4 semantics ----
    const float* row = c_out + (size_t)b * GNUM_;
    float lv[TOPK_]; int li[TOPK_];
#pragma unroll
    for (int k = 0; k < TOPK_; k++) { lv[k] = -1.f; li[k] = 0x7fffffff; }
    for (int i = t; i < GNUM_; i += 256) {
        float p = 1.f / (1.f + expf(-row[i]));
        if (p > lv[TOPK_ - 1]) {
            float cv = p; int ci = i;
#pragma unroll
            for (int k = 0; k < TOPK_; k++) {
                bool sw = (cv > lv[k]);
                float tv = sw ? lv[k] : cv; int ti = sw ? li[k] : ci;
                lv[k] = sw ? cv : lv[k];    li[k] = sw ? ci : li[k];
                cv = tv; ci = ti;
            }
        }
    }
    const int lane = t & 63, wv = t >> 6;
    for (int rnd = 0; rnd < TOPK_; rnd++) {
        float bv = lv[0]; int bi = li[0];
#pragma unroll
        for (int off = 32; off >= 1; off >>= 1) {
            float ov = __shfl_xor(bv, off); int oi = __shfl_xor(bi, off);
            if (ov > bv || (ov == bv && oi < bi)) { bv = ov; bi = oi; }
        }
        if (lane == 0) { bvv[wv] = bv; bii[wv] = bi; }
        __syncthreads();
        float gbv = bvv[0]; int gbi = bii[0];
#pragma unroll
        for (int w2 = 1; w2 < 4; w2++) {
            float ov = bvv[w2]; int oi = bii[w2];
            if (ov > gbv || (ov == gbv && oi < gbi)) { gbv = ov; gbi = oi; }
        }
        if (t == 0) { topv[rnd] = gbv; topi[rnd] = gbi; }
        if (li[0] == gbi) {
#pragma unroll
            for (int k = 0; k < TOPK_ - 1; k++) { lv[k] = lv[k + 1]; li[k] = li[k + 1]; }
            lv[TOPK_ - 1] = -1.f; li[TOPK_ - 1] = 0x7fffffff;
        }
        __syncthreads();
    }

    if (q4 == 0) {
        for (int j = t; j < C_; j += 256) {
            int k = j >> 6, slot = j & 63;
            int lbl = gy[topi[k] * GSZ_ + slot];
            cand_f[(size_t)b * C_ + j] = (float)lbl;
            gcs[(size_t)b * C_ + j] = topv[k];
        }
    }

    // ---- score this quarter's 160 candidates ----
    const int qq = lane >> 4, sub = lane & 15;
    const int cbase = q4 * 160;
    int c0 = cbase + wv * 4 + qq;
    int lbl0 = gy[topi[c0 >> 6] * GSZ_ + (c0 & 63)];
    const float* er = et + (size_t)lbl0 * E_ + sub * 4;
    float4 v0 = *(const float4*)(er);
    float4 v1 = *(const float4*)(er + 64);
    float4 v2 = *(const float4*)(er + 128);
    float4 v3 = *(const float4*)(er + 192);
    for (int pass = 0; pass < 10; pass++) {
        float4 p0, p1, p2, p3;
        if (pass + 1 < 10) {
            int cn = cbase + (pass + 1) * 16 + wv * 4 + qq;
            int lbln = gy[topi[cn >> 6] * GSZ_ + (cn & 63)];
            const float* ern = et + (size_t)lbln * E_ + sub * 4;
            p0 = *(const float4*)(ern);
            p1 = *(const float4*)(ern + 64);
            p2 = *(const float4*)(ern + 128);
            p3 = *(const float4*)(ern + 192);
        }
        float best = -1e30f;
#pragma unroll
        for (int a = 0; a < A_; a++) {
            const float* ep = el + a * E_ + sub * 4;
            float4 w0 = *(const float4*)(ep);
            float4 w1 = *(const float4*)(ep + 64);
            float4 w2 = *(const float4*)(ep + 128);
            float4 w3 = *(const float4*)(ep + 192);
            float pp = v0.x*w0.x + v0.y*w0.y + v0.z*w0.z + v0.w*w0.w
                     + v1.x*w1.x + v1.y*w1.y + v1.z*w1.z + v1.w*w1.w
                     + v2.x*w2.x + v2.y*w2.y + v2.z*w2.z + v2.w*w2.w
                     + v3.x*w3.x + v3.y*w3.y + v3.z*w3.z + v3.w*w3.w;
#pragma unroll
            for (int off = 8; off >= 1; off >>= 1) pp += __shfl_xor(pp, off);
            best = fmaxf(best, pp);
        }
        if (sub == 0) l_out[(size_t)b * C_ + cbase + pass * 16 + wv * 4 + qq] = best;
        v0 = p0; v1 = p1; v2 = p2; v3 = p3;
    }
}

// ---------------------------------------------------------------------------
extern "C" void kernel_launch(void* const* d_in, const int* in_sizes, int n_in,
                              void* d_out, int out_size, void* d_ws, size_t ws_size,
                              hipStream_t stream)
{
    (void)in_sizes; (void)n_in; (void)out_size; (void)ws_size;
    const float* x    = (const float*)d_in[0];
    const float* Watt = (const float*)d_in[1];
    const float* batt = (const float*)d_in[2];
    const float* Wclf = (const float*)d_in[3];
    const float* bclf = (const float*)d_in[4];
    const float* Wenc = (const float*)d_in[5];
    const float* benc = (const float*)d_in[6];
    const float* et   = (const float*)d_in[7];
    const int*   gy   = (const int*)d_in[8];

    float* out    = (float*)d_out;
    float* c_out  = out;                        // [64][8192]
    float* l_out  = out + (size_t)B_ * GNUM_;   // [64][640]
    float* cand_f = l_out + (size_t)B_ * C_;    // [64][640]
    float* gcs    = cand_f + (size_t)B_ * C_;   // [64][640]

    char* ws = (char*)d_ws;
    float*  attT = (float*) (ws);                 // 512 KB
    float*  embw = (float*) (ws + 524288);        // 512 KB
    ushort* Ahw  = (ushort*)(ws + 1048576);       // 768 KB
    ushort* Alw  = (ushort*)(ws + 1835008);       // 768 KB

    attn1_kernel<<<dim3(B_, 4), 256, 0, stream>>>(x, Watt, batt, attT);
    attn2s_kernel<<<dim3(B_, 3), 256, 0, stream>>>(x, attT, Ahw, Alw);
    gemm_mfma_kernel<<<288, 256, 0, stream>>>(Ahw, Alw, Wclf, Wenc, bclf, benc,
                                              c_out, embw);
    scoretop_kernel<<<256, 256, 0, stream>>>(c_out, gy, embw, et,
                                             l_out, cand_f, gcs);
}

// Round 10
// 131.931 us; speedup vs baseline: 1.7397x; 1.0690x over previous
//
#include <hip/hip_runtime.h>

#define B_    64
#define S_    256
#define H_    768
#define A_    8
#define GNUM_ 8192
#define GSZ_  64
#define E_    256
#define TOPK_ 10
#define C_    (TOPK_*GSZ_)   // 640
#define BROWS (GNUM_ + E_)   // 8448

typedef short  bf16x8 __attribute__((ext_vector_type(8)));
typedef float  f32x4  __attribute__((ext_vector_type(4)));

__device__ __forceinline__ ushort f2bf(float x) {
    union { float f; unsigned u; } c; c.f = x;
    unsigned r = c.u + 0x7fff + ((c.u >> 16) & 1);   // RNE
    return (ushort)(r >> 16);
}
__device__ __forceinline__ float bf2f(ushort h) {
    union { float f; unsigned u; } c; c.u = ((unsigned)h) << 16;
    return c.f;
}
__device__ __forceinline__ float asf(unsigned u) {
    union { unsigned u; float f; } c; c.u = u; return c.f;
}
__device__ __forceinline__ unsigned cvt_pk_bf16(float a, float b) {
    unsigned r;
    asm("v_cvt_pk_bf16_f32 %0, %1, %2" : "=v"(r) : "v"(a), "v"(b));
    return r;
}

// ---------------------------------------------------------------------------
// attn1: atten logits + bias.  Block (b, s-chunk of 64) -> attT[b][s][a].
// (R9 verbatim)
// ---------------------------------------------------------------------------
__global__ __launch_bounds__(256) void attn1_kernel(
    const float* __restrict__ x, const float* __restrict__ Watt,
    const float* __restrict__ batt, float* __restrict__ attT)
{
    const int b  = blockIdx.x;
    const int s0 = blockIdx.y * 64;
    const int t  = threadIdx.x;
    const int sl = t & 63;
    const int g  = __builtin_amdgcn_readfirstlane(t >> 6);
    __shared__ float Xt[64][65];
    __shared__ float Pp[8][64][5];

    const float* xb = x + ((size_t)b * S_ + s0) * H_;
    float acc[A_] = {};
    int pr[4], pc[4];
    float4 pref[4];
#pragma unroll
    for (int i = 0; i < 4; i++) {
        int fid = i * 256 + t;
        pr[i] = fid >> 4; pc[i] = (fid & 15) * 4;
    }
#pragma unroll
    for (int i = 0; i < 4; i++)
        pref[i] = *(const float4*)(xb + (size_t)pr[i] * H_ + pc[i]);
    for (int h0 = 0; h0 < H_; h0 += 64) {
        __syncthreads();
#pragma unroll
        for (int i = 0; i < 4; i++) {
            float4 v = pref[i];
            float* dst = &Xt[pr[i]][pc[i]];
            dst[0] = v.x; dst[1] = v.y; dst[2] = v.z; dst[3] = v.w;
        }
        __syncthreads();
        if (h0 + 64 < H_) {
#pragma unroll
            for (int i = 0; i < 4; i++)
                pref[i] = *(const float4*)(xb + (size_t)pr[i] * H_ + h0 + 64 + pc[i]);
        }
        const float* wp = Watt + h0 + g * 16;
#pragma unroll
        for (int h = 0; h < 16; h++) {
            float xv = Xt[sl][g * 16 + h];
#pragma unroll
            for (int a = 0; a < A_; a++) acc[a] += xv * wp[a * H_ + h];
        }
    }
#pragma unroll
    for (int a = 0; a < A_; a++) Pp[a][sl][g] = acc[a];
    __syncthreads();
#pragma unroll
    for (int i = 0; i < 2; i++) {
        int idx = i * 256 + t;
        int a = idx >> 6, s2 = idx & 63;
        float v = Pp[a][s2][0] + Pp[a][s2][1] + Pp[a][s2][2] + Pp[a][s2][3] + batt[a];
        attT[(size_t)b * (S_*A_) + (size_t)(s0 + s2) * A_ + a] = v;
    }
}

// ---------------------------------------------------------------------------
// attn2s: inline softmax + weighted sum + bf16 hi/lo split.
// 512-thread blocks: threads t<256 accumulate s in [0,128), t>=256 s in
// [128,256); halves combined via LDS.  8 waves/block = 2 waves/SIMD.
// ---------------------------------------------------------------------------
__global__ __launch_bounds__(512) void attn2s_kernel(
    const float* __restrict__ x, const float* __restrict__ attT,
    ushort* __restrict__ Ah, ushort* __restrict__ Al)
{
    const int b = blockIdx.x, h0 = blockIdx.y * 256, t = threadIdx.x;
    __shared__ float La[S_ * A_];          // [s][a], 8 KB
    __shared__ float Wm[A_][260];          // [a][s], 8.3 KB
    __shared__ float Cb[A_][256];          // combine buffer, 8 KB

    // load logits (512 float4 slots, one per thread)
    *(float4*)&La[t * 4] =
        *(const float4*)(attT + (size_t)b * (S_*A_) + (size_t)t * 4);
    __syncthreads();
    if (t < 256) {                          // softmax: 8 heads x 32 lanes
        const int a = t >> 5, l = t & 31;
        float mx = -1e30f;
#pragma unroll
        for (int k = 0; k < 8; k++) mx = fmaxf(mx, La[(l + 32*k) * A_ + a]);
#pragma unroll
        for (int off = 16; off >= 1; off >>= 1) mx = fmaxf(mx, __shfl_xor(mx, off));
        float ev[8]; float sm = 0.f;
#pragma unroll
        for (int k = 0; k < 8; k++) { ev[k] = expf(La[(l + 32*k) * A_ + a] - mx); sm += ev[k]; }
#pragma unroll
        for (int off = 16; off >= 1; off >>= 1) sm += __shfl_xor(sm, off);
        float inv = 1.f / sm;
#pragma unroll
        for (int k = 0; k < 8; k++) Wm[a][l + 32*k] = ev[k] * inv;
    }
    __syncthreads();

    const int col = t & 255, half = t >> 8;
    const int sbase = half * 128;
    const float* xb = x + (size_t)b * S_ * H_ + (size_t)sbase * H_ + h0 + col;
    float o[A_] = {};
    float xb0[16], xb1[16];
#define LOADSTRIP(buf, ks) { _Pragma("unroll") \
    for (int i = 0; i < 16; i++) buf[i] = xb[(size_t)((ks)*16 + i) * H_]; }
#define COMPSTRIP(buf, ks) { _Pragma("unroll") \
    for (int sg = 0; sg < 4; sg++) { _Pragma("unroll") \
        for (int a = 0; a < A_; a++) { \
            float4 w2 = *(const float4*)&Wm[a][sbase + (ks)*16 + sg*4]; \
            o[a] += w2.x*buf[sg*4+0] + w2.y*buf[sg*4+1] \
                  + w2.z*buf[sg*4+2] + w2.w*buf[sg*4+3]; } } }
    LOADSTRIP(xb0, 0)
#pragma unroll
    for (int kp = 0; kp < 4; kp++) {
        LOADSTRIP(xb1, 2*kp + 1)
        COMPSTRIP(xb0, 2*kp)
        if (kp < 3) LOADSTRIP(xb0, 2*kp + 2)
        COMPSTRIP(xb1, 2*kp + 1)
    }
#undef LOADSTRIP
#undef COMPSTRIP
    if (half == 1) {
#pragma unroll
        for (int a = 0; a < A_; a++) Cb[a][col] = o[a];
    }
    __syncthreads();
    if (half == 0) {
#pragma unroll
        for (int a = 0; a < A_; a++) {
            float v = o[a] + Cb[a][col];
            ushort hi = f2bf(v);
            ushort lo = f2bf(v - bf2f(hi));
            size_t off = (size_t)(b * 8 + a) * H_ + h0 + col;
            Ah[off] = hi; Al[off] = lo;
        }
    }
}

// ---------------------------------------------------------------------------
// gemm: C = A(512x768) x B^T(8448x768), bf16x3 MFMA (AhBh + AlBh + AhBl).
// (R9 verbatim)
// ---------------------------------------------------------------------------
__global__ __launch_bounds__(256, 1) void gemm_mfma_kernel(
    const ushort* __restrict__ Ah, const ushort* __restrict__ Al,
    const float* __restrict__ Wclf, const float* __restrict__ Wenc,
    const float* __restrict__ bclf, const float* __restrict__ benc,
    float* __restrict__ c_out, float* __restrict__ emb)
{
    const int f = blockIdx.x;
    const int xcd = f & 7, s = f >> 3;
    const int p = xcd + 8 * (s >> 2);          // B panel 0..65 (+invalid tail)
    const int m = s & 3;
    if (p >= BROWS / 128) return;
    const int n0 = p * 128, m0 = m * 128;

    __shared__ __align__(16) ushort lds[2][4][128 * 32];   // 64 KB
    const int t = threadIdx.x;
    const int w = t >> 6, l = t & 63;
    const int mq = (w & 1) * 64, nq = (w >> 1) * 64;

    const int srow = t >> 2, skc = t & 3;
    const int wr_idx = ((srow * 32 + skc * 8) ^ ((srow & 7) << 3));
    const ushort* baseAh = Ah + (size_t)m0 * H_;
    const ushort* baseAl = Al + (size_t)m0 * H_;
    const float*  baseB  = (n0 < GNUM_) ? (Wclf + (size_t)n0 * H_)
                                        : (Wenc + (size_t)(n0 - GNUM_) * H_);

    uint4  stA[2][2];
    float4 stB[2][2];
    auto loadk = [&](int k0) {
        size_t oA = (size_t)srow * H_ + k0 + skc * 8;
        stA[0][0] = *(const uint4*)(baseAh + oA);
        stA[0][1] = *(const uint4*)(baseAh + oA + (size_t)64 * H_);
        stA[1][0] = *(const uint4*)(baseAl + oA);
        stA[1][1] = *(const uint4*)(baseAl + oA + (size_t)64 * H_);
        const float* bp0 = baseB + (size_t)srow * H_ + k0 + skc * 8;
        const float* bp1 = bp0 + (size_t)64 * H_;
        stB[0][0] = *(const float4*)(bp0);
        stB[0][1] = *(const float4*)(bp0 + 4);
        stB[1][0] = *(const float4*)(bp1);
        stB[1][1] = *(const float4*)(bp1 + 4);
    };

    f32x4 acc[4][4] = {};
    loadk(0);
    const int kc = l >> 4, lr = l & 15;

    for (int kt = 0; kt < H_ / 32; ++kt) {
        ushort* bufp = &lds[kt & 1][0][0];
#pragma unroll
        for (int xx = 0; xx < 2; xx++) {
            *(uint4*)(bufp + xx * 4096 + wr_idx)        = stA[xx][0];
            *(uint4*)(bufp + xx * 4096 + 2048 + wr_idx) = stA[xx][1];
        }
#pragma unroll
        for (int rp = 0; rp < 2; rp++) {
            float fv[8] = { stB[rp][0].x, stB[rp][0].y, stB[rp][0].z, stB[rp][0].w,
                            stB[rp][1].x, stB[rp][1].y, stB[rp][1].z, stB[rp][1].w };
            uint4 hi, lo;
            unsigned* hip = (unsigned*)&hi;
            unsigned* lop = (unsigned*)&lo;
#pragma unroll
            for (int j = 0; j < 4; j++) {
                unsigned pk = cvt_pk_bf16(fv[2*j], fv[2*j+1]);
                hip[j] = pk;
                float r0 = fv[2*j]   - asf(pk << 16);
                float r1 = fv[2*j+1] - asf(pk & 0xffff0000u);
                lop[j] = cvt_pk_bf16(r0, r1);
            }
            *(uint4*)(bufp + 2 * 4096 + rp * 2048 + wr_idx) = hi;
            *(uint4*)(bufp + 3 * 4096 + rp * 2048 + wr_idx) = lo;
        }
        __syncthreads();
        if (kt + 1 < H_ / 32) loadk((kt + 1) * 32);

        bf16x8 fah[4], fal[4], fbh[4], fbl[4];
#pragma unroll
        for (int mt = 0; mt < 4; mt++) {
            int r = mq + mt * 16 + lr;
            int idx = ((r * 32 + kc * 8) ^ ((r & 7) << 3));
            fah[mt] = *(const bf16x8*)(bufp + idx);
            fal[mt] = *(const bf16x8*)(bufp + 4096 + idx);
        }
#pragma unroll
        for (int nt = 0; nt < 4; nt++) {
            int r = nq + nt * 16 + lr;
            int idx = ((r * 32 + kc * 8) ^ ((r & 7) << 3));
            fbh[nt] = *(const bf16x8*)(bufp + 2 * 4096 + idx);
            fbl[nt] = *(const bf16x8*)(bufp + 3 * 4096 + idx);
        }
#pragma unroll
        for (int mt = 0; mt < 4; mt++)
#pragma unroll
            for (int nt = 0; nt < 4; nt++) {
                acc[mt][nt] = __builtin_amdgcn_mfma_f32_16x16x32_bf16(fah[mt], fbh[nt], acc[mt][nt], 0, 0, 0);
                acc[mt][nt] = __builtin_amdgcn_mfma_f32_16x16x32_bf16(fal[mt], fbh[nt], acc[mt][nt], 0, 0, 0);
                acc[mt][nt] = __builtin_amdgcn_mfma_f32_16x16x32_bf16(fah[mt], fbl[nt], acc[mt][nt], 0, 0, 0);
            }
    }

    const int q = l >> 4;
    if (n0 < GNUM_) {
#pragma unroll
        for (int mt = 0; mt < 4; mt++)
#pragma unroll
            for (int nt = 0; nt < 4; nt++) {
                f32x4 a = acc[mt][nt];
                float v = fmaxf(fmaxf(a[0], a[1]), fmaxf(a[2], a[3]));
                v = fmaxf(v, __shfl_xor(v, 16));
                if ((q & 1) == 0) {
                    int mg = m0 + mq + mt * 16 + (q >> 1) * 8;
                    int n  = n0 + nq + nt * 16 + lr;
                    c_out[(size_t)(mg >> 3) * GNUM_ + n] = v + bclf[n];
                }
            }
    } else {
#pragma unroll
        for (int mt = 0; mt < 4; mt++)
#pragma unroll
            for (int nt = 0; nt < 4; nt++) {
                int n = n0 - GNUM_ + nq + nt * 16 + lr;
                float bn = benc[n];
#pragma unroll
                for (int r2 = 0; r2 < 4; r2++) {
                    int mg = m0 + mq + mt * 16 + q * 4 + r2;
                    emb[(size_t)mg * E_ + n] = acc[mt][nt][r2] + bn;
                }
            }
    }
}

// ---------------------------------------------------------------------------
// scoretop: block (b, eighth).  Each block recomputes row-b top-10 from
// c_out (identical scan/tie-break), block q8==0 writes cand_f/gcs, all
// blocks score their 80-candidate slice.  512 blocks = 2/CU.
// ---------------------------------------------------------------------------
__global__ __launch_bounds__(256) void scoretop_kernel(
    const float* __restrict__ c_out, const int* __restrict__ gy,
    const float* __restrict__ embw, const float* __restrict__ et,
    float* __restrict__ l_out, float* __restrict__ cand_f,
    float* __restrict__ gcs)
{
    const int b = blockIdx.x >> 3, q8 = blockIdx.x & 7, t = threadIdx.x;
    __shared__ float el[A_ * E_];          // 8 KB
    __shared__ float bvv[4]; __shared__ int bii[4];
    __shared__ float topv[TOPK_]; __shared__ int topi[TOPK_];

#pragma unroll
    for (int i = 0; i < 2; i++) {
        int fid = i * 256 + t;
        *(float4*)&el[fid * 4] = *(const float4*)(embw + (size_t)b * (A_*E_) + fid * 4);
    }

    // ---- top-10 of sigmoid(c_out[b]) ----
    const float* row = c_out + (size_t)b * GNUM_;
    float lv[TOPK_]; int li[TOPK_];
#pragma unroll
    for (int k = 0; k < TOPK_; k++) { lv[k] = -1.f; li[k] = 0x7fffffff; }
    for (int i = t; i < GNUM_; i += 256) {
        float p = 1.f / (1.f + expf(-row[i]));
        if (p > lv[TOPK_ - 1]) {
            float cv = p; int ci = i;
#pragma unroll
            for (int k = 0; k < TOPK_; k++) {
                bool sw = (cv > lv[k]);
                float tv = sw ? lv[k] : cv; int ti = sw ? li[k] : ci;
                lv[k] = sw ? cv : lv[k];    li[k] = sw ? ci : li[k];
                cv = tv; ci = ti;
            }
        }
    }
    const int lane = t & 63, wv = t >> 6;
    for (int rnd = 0; rnd < TOPK_; rnd++) {
        float bv = lv[0]; int bi = li[0];
#pragma unroll
        for (int off = 32; off >= 1; off >>= 1) {
            float ov = __shfl_xor(bv, off); int oi = __shfl_xor(bi, off);
            if (ov > bv || (ov == bv && oi < bi)) { bv = ov; bi = oi; }
        }
        if (lane == 0) { bvv[wv] = bv; bii[wv] = bi; }
        __syncthreads();
        float gbv = bvv[0]; int gbi = bii[0];
#pragma unroll
        for (int w2 = 1; w2 < 4; w2++) {
            float ov = bvv[w2]; int oi = bii[w2];
            if (ov > gbv || (ov == gbv && oi < gbi)) { gbv = ov; gbi = oi; }
        }
        if (t == 0) { topv[rnd] = gbv; topi[rnd] = gbi; }
        if (li[0] == gbi) {
#pragma unroll
            for (int k = 0; k < TOPK_ - 1; k++) { lv[k] = lv[k + 1]; li[k] = li[k + 1]; }
            lv[TOPK_ - 1] = -1.f; li[TOPK_ - 1] = 0x7fffffff;
        }
        __syncthreads();
    }

    if (q8 == 0) {
        for (int j = t; j < C_; j += 256) {
            int k = j >> 6, slot = j & 63;
            int lbl = gy[topi[k] * GSZ_ + slot];
            cand_f[(size_t)b * C_ + j] = (float)lbl;
            gcs[(size_t)b * C_ + j] = topv[k];
        }
    }

    // ---- score this block's 80 candidates ----
    const int qq = lane >> 4, sub = lane & 15;
    const int cbase = q8 * 80;
    int c0 = cbase + wv * 4 + qq;
    int lbl0 = gy[topi[c0 >> 6] * GSZ_ + (c0 & 63)];
    const float* er = et + (size_t)lbl0 * E_ + sub * 4;
    float4 v0 = *(const float4*)(er);
    float4 v1 = *(const float4*)(er + 64);
    float4 v2 = *(const float4*)(er + 128);
    float4 v3 = *(const float4*)(er + 192);
    for (int pass = 0; pass < 5; pass++) {
        float4 p0, p1, p2, p3;
        if (pass + 1 < 5) {
            int cn = cbase + (pass + 1) * 16 + wv * 4 + qq;
            int lbln = gy[topi[cn >> 6] * GSZ_ + (cn & 63)];
            const float* ern = et + (size_t)lbln * E_ + sub * 4;
            p0 = *(const float4*)(ern);
            p1 = *(const float4*)(ern + 64);
            p2 = *(const float4*)(ern + 128);
            p3 = *(const float4*)(ern + 192);
        }
        float best = -1e30f;
#pragma unroll
        for (int a = 0; a < A_; a++) {
            const float* ep = el + a * E_ + sub * 4;
            float4 w0 = *(const float4*)(ep);
            float4 w1 = *(const float4*)(ep + 64);
            float4 w2 = *(const float4*)(ep + 128);
            float4 w3 = *(const float4*)(ep + 192);
            float pp = v0.x*w0.x + v0.y*w0.y + v0.z*w0.z + v0.w*w0.w
                     + v1.x*w1.x + v1.y*w1.y + v1.z*w1.z + v1.w*w1.w
                     + v2.x*w2.x + v2.y*w2.y + v2.z*w2.z + v2.w*w2.w
                     + v3.x*w3.x + v3.y*w3.y + v3.z*w3.z + v3.w*w3.w;
#pragma unroll
            for (int off = 8; off >= 1; off >>= 1) pp += __shfl_xor(pp, off);
            best = fmaxf(best, pp);
        }
        if (sub == 0) l_out[(size_t)b * C_ + cbase + pass * 16 + wv * 4 + qq] = best;
        v0 = p0; v1 = p1; v2 = p2; v3 = p3;
    }
}

// ---------------------------------------------------------------------------
extern "C" void kernel_launch(void* const* d_in, const int* in_sizes, int n_in,
                              void* d_out, int out_size, void* d_ws, size_t ws_size,
                              hipStream_t stream)
{
    (void)in_sizes; (void)n_in; (void)out_size; (void)ws_size;
    const float* x    = (const float*)d_in[0];
    const float* Watt = (const float*)d_in[1];
    const float* batt = (const float*)d_in[2];
    const float* Wclf = (const float*)d_in[3];
    const float* bclf = (const float*)d_in[4];
    const float* Wenc = (const float*)d_in[5];
    const float* benc = (const float*)d_in[6];
    const float* et   = (const float*)d_in[7];
    const int*   gy   = (const int*)d_in[8];

    float* out    = (float*)d_out;
    float* c_out  = out;                        // [64][8192]
    float* l_out  = out + (size_t)B_ * GNUM_;   // [64][640]
    float* cand_f = l_out + (size_t)B_ * C_;    // [64][640]
    float* gcs    = cand_f + (size_t)B_ * C_;   // [64][640]

    char* ws = (char*)d_ws;
    float*  attT = (float*) (ws);                 // 512 KB
    float*  embw = (float*) (ws + 524288);        // 512 KB
    ushort* Ahw  = (ushort*)(ws + 1048576);       // 768 KB
    ushort* Alw  = (ushort*)(ws + 1835008);       // 768 KB

    attn1_kernel<<<dim3(B_, 4), 256, 0, stream>>>(x, Watt, batt, attT);
    attn2s_kernel<<<dim3(B_, 3), 512, 0, stream>>>(x, attT, Ahw, Alw);
    gemm_mfma_kernel<<<288, 256, 0, stream>>>(Ahw, Alw, Wclf, Wenc, bclf, benc,
                                              c_out, embw);
    scoretop_kernel<<<512, 256, 0, stream>>>(c_out, gy, embw, et,
                                             l_out, cand_f, gcs);
}